// Round 7
// baseline (128.515 us; speedup 1.0000x reference)
//
#include <hip/hip_runtime.h>
#include <math.h>

// Problem constants
#define DD     2048
#define EE     64
#define NTOK   8192
#define BM     32               // tokens per m-tile
#define KSPLIT 4                // K-split across blockIdx.y
#define KQ     512              // k per block
#define BK     32               // k per staged chunk
#define NCH    (KQ / BK)        // 16 chunks

// Output layout (all read back as float32 by harness)
#define PROB_OFF 0
#define IDX_OFF  524288
#define MASK_OFF 540672
#define MASK_K_STRIDE (NTOK * EE)

// LDS byte layout (40960 B total -> 4 blocks/CU):
//   xbuf[2] @ 0 / 4096 (4 KB each), bbuf[2] @ 8192 / 24576 (16 KB each)
#define XBUF_OFF(b) ((b) * 4096)
#define BBUF_OFF(b) (8192 + (b) * 16384)
#define LDS_BYTES   40960

typedef __bf16 bf16x8 __attribute__((ext_vector_type(8)));
typedef float  f32x16 __attribute__((ext_vector_type(16)));

__device__ __forceinline__ unsigned f2bf_rne(float f) {
  unsigned u = __float_as_uint(f);
  return (u + 0x7fffu + ((u >> 16) & 1u)) >> 16;   // low 16 bits = bf16
}
__device__ __forceinline__ float bf2f(unsigned h) {
  return __uint_as_float(h << 16);
}

// async 16B global->LDS DMA (no VGPR round-trip; tracked by vmcnt)
__device__ __forceinline__ void gl_lds16(const void* g, void* l) {
  __builtin_amdgcn_global_load_lds(
      (const __attribute__((address_space(1))) unsigned int*)g,
      (__attribute__((address_space(3))) unsigned int*)l,
      16, 0, 0);
}

// ---------------------------------------------------------------------------
// prep_w: weights -> MFMA-fragment-ready bf16 hi/lo in workspace (1 MB).
// Fragment bijection (validated end-to-end by R1-R6 passes):
//   slot (g, nt, mat, lane, i)  <->  B[k][c],  k = 16*g + 8*(lane>>5) + i,
//   c = 32*nt + (lane&31),  (c<64 -> gate, else noise).
// Byte addr = ((g*4 + nt)*2 + mat)*1024 + lane*16 + 2*i.
// ---------------------------------------------------------------------------
__global__ __launch_bounds__(256) void prep_w(
    const float* __restrict__ wg, const float* __restrict__ wn,
    unsigned char* __restrict__ wsb)
{
  const int t  = blockIdx.x * 256 + threadIdx.x;   // 0..32767
  const int l  = t & 63;
  const int nt = (t >> 6) & 3;
  const int g  = t >> 8;                           // 0..127 (16-k steps)
  const int colg = nt * 32 + (l & 31);             // 0..127
  const int kb   = g * 16 + 8 * (l >> 5);
  const float* wsrc = (colg < EE) ? (wg + colg) : (wn + (colg - EE));

  unsigned hv[8], lv[8];
#pragma unroll
  for (int i = 0; i < 8; ++i) {
    const float v = wsrc[(size_t)(kb + i) * EE];
    const unsigned h = f2bf_rne(v);
    hv[i] = h;
    lv[i] = f2bf_rne(v - bf2f(h));
  }
  uint4 hq, lq;
  hq.x = hv[0] | (hv[1] << 16); hq.y = hv[2] | (hv[3] << 16);
  hq.z = hv[4] | (hv[5] << 16); hq.w = hv[6] | (hv[7] << 16);
  lq.x = lv[0] | (lv[1] << 16); lq.y = lv[2] | (lv[3] << 16);
  lq.z = lv[4] | (lv[5] << 16); lq.w = lv[6] | (lv[7] << 16);

  const size_t base = ((size_t)(g * 4 + nt) * 2) * 1024 + (size_t)l * 16;
  *reinterpret_cast<uint4*>(wsb + base)        = hq;   // hi
  *reinterpret_cast<uint4*>(wsb + base + 1024) = lq;   // lo
}

union BF8 { bf16x8 v; ushort u[8]; };

__device__ __forceinline__ void cvt_hilo(const float4& a, const float4& b,
                                         bf16x8& hi, bf16x8& lo) {
  const float f[8] = {a.x, a.y, a.z, a.w, b.x, b.y, b.z, b.w};
  BF8 H, L;
#pragma unroll
  for (int i = 0; i < 8; ++i) {
    const unsigned u = __float_as_uint(f[i]);
    H.u[i] = (ushort)(u >> 16);                                 // exact prefix
    L.v[i] = (__bf16)(f[i] - __uint_as_float(u & 0xffff0000u)); // residual, RNE
  }
  hi = H.v; lo = L.v;
}

__device__ __forceinline__ bf16x8 bc(const uint4& q) {
  return __builtin_bit_cast(bf16x8, q);
}

// ---------------------------------------------------------------------------
// router_gemm v7: m97 skeleton, 4 blocks/CU drain-overlap. R6 post-mortem:
// the one-chunk gl_lds pipeline stalls at every barrier's vmcnt(0) drain and
// at 2 blocks/CU nothing hides it (m114: need ~3+). BK=32 halves LDS to
// 40 KB -> 4 blocks/CU; KSPLIT=4 -> grid 1024 = exactly 4/CU. Per chunk:
// stage x 4 KB (XOR-preswizzled source, rule #21; reads 2-way = free) +
// B 16 KB (linear; contiguous-b128 reads) = 5 gl_lds/thread; compute 2
// ksteps x {2 A-ds_read + 2 B-ds_read + cvt + 3 mfma}. One barrier/chunk;
// 4 resident blocks mutually hide each other's drains.
// ---------------------------------------------------------------------------
__global__ __launch_bounds__(256, 4) void router_gemm(
    const float* __restrict__ x,
    const unsigned char* __restrict__ wsb,
    float* __restrict__ part)          // [NTOK][KSPLIT][128]
{
  __shared__ unsigned char lds[LDS_BYTES];

  const int tid  = threadIdx.x;
  const int wid  = tid >> 6;           // 0..3 = nt
  const int lane = tid & 63;
  const int nt   = wid;
  const int tok0 = blockIdx.x * BM;
  const int ks   = blockIdx.y;
  const int kbase = ks * KQ;

  // ---- staging roles ----
  // x: thread t -> row = t>>3 (32 rows), slot = t&7 (8 x 16B per 128-B row);
  // source pre-swizzled: content = x[row][kbase + c*32 + ((slot^(row&7))*4)];
  // LDS dest linear (wave base + lane*16, the gl_lds requirement).
  const int xrow = tid >> 3;
  const int xslot = tid & 7;
  const float* xsrc = x + (size_t)(tok0 + xrow) * DD + kbase
                        + ((xslot ^ (xrow & 7)) << 2);
  // B: chunk c = g-steps 2c..2c+1 -> ws bytes (ks*KQ/16 + 2c)*8192 .. +16384
  const unsigned char* bsrc = wsb + (size_t)(ks * (KQ / 16)) * 8192
                                  + (size_t)tid * 16;

  // ---- compute-role constants ----
  const int arow = lane & 31;          // token within tile
  const int atl  = lane >> 5;
  const int xswz = arow & 7;

  f32x16 acc = {0.f,0.f,0.f,0.f,0.f,0.f,0.f,0.f,
                0.f,0.f,0.f,0.f,0.f,0.f,0.f,0.f};

  // ---- stage chunk 0 ----
  {
    gl_lds16(xsrc, &lds[XBUF_OFF(0) + tid * 16]);
#pragma unroll
    for (int j = 0; j < 4; ++j)
      gl_lds16(bsrc + j * 4096, &lds[BBUF_OFF(0) + j * 4096 + tid * 16]);
  }
  __syncthreads();   // compiler drains vmcnt(0) here

  for (int c = 0; c < NCH; ++c) {
    const int cb = c & 1;

    if (c + 1 < NCH) {   // stage chunk c+1 into the other buffer (async DMA)
      const int nb = cb ^ 1;
      gl_lds16(xsrc + (c + 1) * BK, &lds[XBUF_OFF(nb) + tid * 16]);
      const unsigned char* bs = bsrc + (size_t)(c + 1) * 16384;
#pragma unroll
      for (int j = 0; j < 4; ++j)
        gl_lds16(bs + j * 4096, &lds[BBUF_OFF(nb) + j * 4096 + tid * 16]);
    }

    // ---- compute chunk c from buffer cb (LDS only) ----
    const unsigned char* xb = &lds[XBUF_OFF(cb)];
    const unsigned char* bb = &lds[BBUF_OFF(cb)];
#pragma unroll
    for (int s = 0; s < 2; ++s) {
      const int sl0 = (4 * s + 2 * atl) ^ xswz;
      const int sl1 = (4 * s + 2 * atl + 1) ^ xswz;
      const float4 xa = *reinterpret_cast<const float4*>(
          xb + arow * 128 + sl0 * 16);
      const float4 xv = *reinterpret_cast<const float4*>(
          xb + arow * 128 + sl1 * 16);
      const unsigned char* q = bb + s * 8192 + nt * 2048 + lane * 16;
      const uint4 bh = *reinterpret_cast<const uint4*>(q);
      const uint4 bl = *reinterpret_cast<const uint4*>(q + 1024);

      bf16x8 ahi, alo;
      cvt_hilo(xa, xv, ahi, alo);
      acc = __builtin_amdgcn_mfma_f32_32x32x16_bf16(ahi, bc(bh), acc, 0, 0, 0);
      acc = __builtin_amdgcn_mfma_f32_32x32x16_bf16(ahi, bc(bl), acc, 0, 0, 0);
      acc = __builtin_amdgcn_mfma_f32_32x32x16_bf16(alo, bc(bh), acc, 0, 0, 0);
    }
    __syncthreads();   // readers of cb done; staged c+1 drained
  }

  // ---- tail: acc -> LDS [32][128] f32 (overlays buffers), coalesced store ----
  // C/D map (validated R1-R6): col = lane&31, row = (q&3)+8*(q>>2)+4*(lane>>5)
  float* Lp = reinterpret_cast<float*>(lds);
  const int ccol = nt * 32 + (lane & 31);
#pragma unroll
  for (int q = 0; q < 16; ++q) {
    const int r = (q & 3) + 8 * (q >> 2) + 4 * atl;
    Lp[r * 128 + ccol] = acc[q];
  }
  __syncthreads();
#pragma unroll
  for (int rr = 0; rr < 8; ++rr) {
    const int r = 8 * wid + rr;
    const float2 v = *reinterpret_cast<const float2*>(&Lp[r * 128 + 2 * lane]);
    *reinterpret_cast<float2*>(
        part + ((size_t)(tok0 + r) * KSPLIT + ks) * 128 + 2 * lane) = v;
  }
}

// ---------------------------------------------------------------------------
// Epilogue (R0/R4/R6-proven): one wave per token. Sum KSPLIT partials,
// softplus-noise, top-2 (desc value, asc index), softmax over 2, scatter.
// ---------------------------------------------------------------------------
__global__ __launch_bounds__(256) void router_epilogue(
    const float* __restrict__ part,      // [NTOK][KSPLIT][128]
    const float* __restrict__ noise_eps, // [NTOK][EE]
    float* __restrict__ out)
{
  const int t    = blockIdx.x * 4 + (threadIdx.x >> 6);
  const int lane = threadIdx.x & 63;

  const float* p = part + (size_t)t * KSPLIT * 128;
  float g = 0.0f, nraw = 0.0f;
#pragma unroll
  for (int s = 0; s < KSPLIT; ++s) {
    g    += p[s * 128 + lane];
    nraw += p[s * 128 + EE + lane];
  }
  const float ep = noise_eps[(size_t)t * EE + lane];

  const float sp = fmaxf(nraw, 0.0f) + log1pf(expf(-fabsf(nraw)));
  const float z  = fmaf(sp, ep, g);

  float v1 = z; int i1 = lane;
#pragma unroll
  for (int off = 32; off >= 1; off >>= 1) {
    const float ov = __shfl_xor(v1, off, 64);
    const int   oi = __shfl_xor(i1, off, 64);
    if (ov > v1 || (ov == v1 && oi < i1)) { v1 = ov; i1 = oi; }
  }
  float v2 = (lane == i1) ? -INFINITY : z; int i2 = lane;
#pragma unroll
  for (int off = 32; off >= 1; off >>= 1) {
    const float ov = __shfl_xor(v2, off, 64);
    const int   oi = __shfl_xor(i2, off, 64);
    if (ov > v2 || (ov == v2 && oi < i2)) { v2 = ov; i2 = oi; }
  }

  const float e2 = expf(v2 - v1);
  const float denom = 1.0f + e2;
  const float p1 = 1.0f / denom;
  const float p2 = e2 / denom;

  out[PROB_OFF + (size_t)t * EE + lane] =
      (lane == i1) ? p1 : ((lane == i2) ? p2 : 0.0f);

  if (lane == 0) {
    out[IDX_OFF + t * 2 + 0] = (float)i1;
    out[IDX_OFF + t * 2 + 1] = (float)i2;
  }

  out[MASK_OFF + 0 * MASK_K_STRIDE + (size_t)t * EE + lane] = (lane == i1) ? 1.0f : 0.0f;
  out[MASK_OFF + 1 * MASK_K_STRIDE + (size_t)t * EE + lane] = (lane == i2) ? 1.0f : 0.0f;
}

// ---------------------------------------------------------------------------
extern "C" void kernel_launch(void* const* d_in, const int* in_sizes, int n_in,
                              void* d_out, int out_size, void* d_ws, size_t ws_size,
                              hipStream_t stream) {
  const float* x   = (const float*)d_in[0];
  const float* eps = (const float*)d_in[1];
  const float* wg  = (const float*)d_in[2];
  const float* wn  = (const float*)d_in[3];

  unsigned char* wsb = (unsigned char*)d_ws;            // 1 MB weight frags
  float* part = (float*)(wsb + (1 << 20));              // 16 MB partials

  prep_w<<<dim3(128), dim3(256), 0, stream>>>(wg, wn, wsb);
  router_gemm<<<dim3(NTOK / BM, KSPLIT), dim3(256), 0, stream>>>(x, wsb, part);
  router_epilogue<<<dim3(NTOK / 4), dim3(256), 0, stream>>>(part, eps,
                                                            (float*)d_out);
}

// Round 8
// 123.457 us; speedup vs baseline: 1.0410x; 1.0410x over previous
//
#include <hip/hip_runtime.h>
#include <math.h>

// Problem constants
#define DD     2048
#define EE     64
#define NTOK   8192
#define BM     64               // tokens per m-tile (doubled: halves B traffic)
#define KSPLIT 4                // K-split across blockIdx.y
#define KQ     512              // k per block
#define BK     32               // k per staged chunk
#define NCH    (KQ / BK)        // 16 chunks

// Output layout (all read back as float32 by harness)
#define PROB_OFF 0
#define IDX_OFF  524288
#define MASK_OFF 540672
#define MASK_K_STRIDE (NTOK * EE)

// LDS byte layout (49152 B -> 2 blocks/CU on 160 KB):
//   xbuf[2] @ 0 / 8192 (8 KB each), bbuf[2] @ 16384 / 32768 (16 KB each)
#define XBUF_OFF(b) ((b) * 8192)
#define BBUF_OFF(b) (16384 + (b) * 16384)
#define LDS_BYTES   49152

typedef __bf16 bf16x8 __attribute__((ext_vector_type(8)));
typedef float  f32x16 __attribute__((ext_vector_type(16)));

__device__ __forceinline__ unsigned f2bf_rne(float f) {
  unsigned u = __float_as_uint(f);
  return (u + 0x7fffu + ((u >> 16) & 1u)) >> 16;   // low 16 bits = bf16
}
__device__ __forceinline__ float bf2f(unsigned h) {
  return __uint_as_float(h << 16);
}

// async 16B global->LDS DMA (no VGPR round-trip; tracked by vmcnt)
__device__ __forceinline__ void gl_lds16(const void* g, void* l) {
  __builtin_amdgcn_global_load_lds(
      (const __attribute__((address_space(1))) unsigned int*)g,
      (__attribute__((address_space(3))) unsigned int*)l,
      16, 0, 0);
}

// ---------------------------------------------------------------------------
// prep_w: weights -> MFMA-fragment-ready bf16 hi/lo in workspace (1 MB).
// Fragment bijection (validated end-to-end by R1-R7 passes):
//   slot (g, nt, mat, lane, i)  <->  B[k][c],  k = 16*g + 8*(lane>>5) + i,
//   c = 32*nt + (lane&31),  (c<64 -> gate, else noise).
// Byte addr = ((g*4 + nt)*2 + mat)*1024 + lane*16 + 2*i.
// ---------------------------------------------------------------------------
__global__ __launch_bounds__(256) void prep_w(
    const float* __restrict__ wg, const float* __restrict__ wn,
    unsigned char* __restrict__ wsb)
{
  const int t  = blockIdx.x * 256 + threadIdx.x;   // 0..32767
  const int l  = t & 63;
  const int nt = (t >> 6) & 3;
  const int g  = t >> 8;                           // 0..127 (16-k steps)
  const int colg = nt * 32 + (l & 31);             // 0..127
  const int kb   = g * 16 + 8 * (l >> 5);
  const float* wsrc = (colg < EE) ? (wg + colg) : (wn + (colg - EE));

  unsigned hv[8], lv[8];
#pragma unroll
  for (int i = 0; i < 8; ++i) {
    const float v = wsrc[(size_t)(kb + i) * EE];
    const unsigned h = f2bf_rne(v);
    hv[i] = h;
    lv[i] = f2bf_rne(v - bf2f(h));
  }
  uint4 hq, lq;
  hq.x = hv[0] | (hv[1] << 16); hq.y = hv[2] | (hv[3] << 16);
  hq.z = hv[4] | (hv[5] << 16); hq.w = hv[6] | (hv[7] << 16);
  lq.x = lv[0] | (lv[1] << 16); lq.y = lv[2] | (lv[3] << 16);
  lq.z = lv[4] | (lv[5] << 16); lq.w = lv[6] | (lv[7] << 16);

  const size_t base = ((size_t)(g * 4 + nt) * 2) * 1024 + (size_t)l * 16;
  *reinterpret_cast<uint4*>(wsb + base)        = hq;   // hi
  *reinterpret_cast<uint4*>(wsb + base + 1024) = lq;   // lo
}

union BF8 { bf16x8 v; ushort u[8]; };

__device__ __forceinline__ void cvt_hilo(const float4& a, const float4& b,
                                         bf16x8& hi, bf16x8& lo) {
  const float f[8] = {a.x, a.y, a.z, a.w, b.x, b.y, b.z, b.w};
  BF8 H, L;
#pragma unroll
  for (int i = 0; i < 8; ++i) {
    const unsigned u = __float_as_uint(f[i]);
    H.u[i] = (ushort)(u >> 16);                                 // exact prefix
    L.v[i] = (__bf16)(f[i] - __uint_as_float(u & 0xffff0000u)); // residual, RNE
  }
  hi = H.v; lo = L.v;
}

__device__ __forceinline__ bf16x8 bc(const uint4& q) {
  return __builtin_bit_cast(bf16x8, q);
}

// ---------------------------------------------------------------------------
// router_gemm v8: bytes-into-CU reduction. R2-R7 fit: GEMM time = total VMEM
// bytes / ~8 TB/s CU-ingress, invariant to occupancy/pipelining. BM=64
// halves the dominant term (B frags: 268 -> 134 MB); traffic 335 -> 217 MB.
// Grid (128 m, 4 ksplit) = 512 blocks = 2/CU; block 512 thr = 8 waves
// (mh2 x nt4). m97 skeleton as R7: per BK=32 chunk stage x 8 KB (XOR-
// preswizzled source, validated) + B 16 KB (linear) = 3 gl_lds/thread;
// compute 2 ksteps x {2A + 2B ds_read_b128 + cvt + 3 mfma}; 1 barrier/chunk.
// ---------------------------------------------------------------------------
__global__ __launch_bounds__(512, 4) void router_gemm(
    const float* __restrict__ x,
    const unsigned char* __restrict__ wsb,
    float* __restrict__ part)          // [NTOK][KSPLIT][128]
{
  __shared__ unsigned char lds[LDS_BYTES];

  const int tid  = threadIdx.x;
  const int wid  = tid >> 6;           // 0..7
  const int lane = tid & 63;
  const int mh   = wid >> 2;           // m-sub (32 tokens)
  const int nt   = wid & 3;            // 32-col tile
  const int tok0 = blockIdx.x * BM;
  const int ks   = blockIdx.y;
  const int kbase = ks * KQ;

  // ---- staging roles ----
  // x: thread t -> row = t>>3 (64 rows), slot = t&7 (8 x 16B per 128-B row);
  // source pre-swizzled: content = x[row][kbase + c*32 + ((slot^(row&7))*4)]
  const int xrow  = tid >> 3;
  const int xslot = tid & 7;
  const float* xsrc = x + (size_t)(tok0 + xrow) * DD + kbase
                        + ((xslot ^ (xrow & 7)) << 2);
  // B: ks slice = g-steps [ks*32, ks*32+32); chunk c = 2 g-steps = 16 KB
  const unsigned char* bsrc = wsb + (size_t)(ks * (KQ / 16)) * 8192
                                  + (size_t)tid * 16;

  // ---- compute-role constants ----
  const int arow = lane & 31;          // token within m-sub
  const int atl  = lane >> 5;
  const int xswz = arow & 7;           // row&7 invariant to mh (32 = 0 mod 8)

  f32x16 acc = {0.f,0.f,0.f,0.f,0.f,0.f,0.f,0.f,
                0.f,0.f,0.f,0.f,0.f,0.f,0.f,0.f};

  // ---- stage chunk 0 ----
  {
    gl_lds16(xsrc, &lds[XBUF_OFF(0) + tid * 16]);
    gl_lds16(bsrc,        &lds[BBUF_OFF(0) + tid * 16]);
    gl_lds16(bsrc + 8192, &lds[BBUF_OFF(0) + 8192 + tid * 16]);
  }
  __syncthreads();   // compiler drains vmcnt(0) here

  for (int c = 0; c < NCH; ++c) {
    const int cb = c & 1;

    if (c + 1 < NCH) {   // stage chunk c+1 into the other buffer (async DMA)
      const int nb = cb ^ 1;
      gl_lds16(xsrc + (c + 1) * BK, &lds[XBUF_OFF(nb) + tid * 16]);
      const unsigned char* bs = bsrc + (size_t)(c + 1) * 16384;
      gl_lds16(bs,        &lds[BBUF_OFF(nb) + tid * 16]);
      gl_lds16(bs + 8192, &lds[BBUF_OFF(nb) + 8192 + tid * 16]);
    }

    // ---- compute chunk c from buffer cb (LDS only) ----
    const unsigned char* xb = &lds[XBUF_OFF(cb)];
    const unsigned char* bb = &lds[BBUF_OFF(cb)];
#pragma unroll
    for (int s = 0; s < 2; ++s) {
      const int sl0 = (4 * s + 2 * atl) ^ xswz;
      const int sl1 = (4 * s + 2 * atl + 1) ^ xswz;
      const float4 xa = *reinterpret_cast<const float4*>(
          xb + (32 * mh + arow) * 128 + sl0 * 16);
      const float4 xv = *reinterpret_cast<const float4*>(
          xb + (32 * mh + arow) * 128 + sl1 * 16);
      const unsigned char* q = bb + s * 8192 + nt * 2048 + lane * 16;
      const uint4 bh = *reinterpret_cast<const uint4*>(q);
      const uint4 bl = *reinterpret_cast<const uint4*>(q + 1024);

      bf16x8 ahi, alo;
      cvt_hilo(xa, xv, ahi, alo);
      acc = __builtin_amdgcn_mfma_f32_32x32x16_bf16(ahi, bc(bh), acc, 0, 0, 0);
      acc = __builtin_amdgcn_mfma_f32_32x32x16_bf16(ahi, bc(bl), acc, 0, 0, 0);
      acc = __builtin_amdgcn_mfma_f32_32x32x16_bf16(alo, bc(bh), acc, 0, 0, 0);
    }
    __syncthreads();   // readers of cb done; staged c+1 drained
  }

  // ---- tail: acc -> LDS [64][128] f32 (overlays buffers), coalesced store ----
  // C/D map (validated R1-R7): col = lane&31, row = (q&3)+8*(q>>2)+4*(lane>>5)
  float* Lp = reinterpret_cast<float*>(lds);
  const int ccol = nt * 32 + (lane & 31);
#pragma unroll
  for (int q = 0; q < 16; ++q) {
    const int r = 32 * mh + (q & 3) + 8 * (q >> 2) + 4 * atl;
    Lp[r * 128 + ccol] = acc[q];
  }
  __syncthreads();
#pragma unroll
  for (int rr = 0; rr < 8; ++rr) {
    const int r = 8 * wid + rr;
    const float2 v = *reinterpret_cast<const float2*>(&Lp[r * 128 + 2 * lane]);
    *reinterpret_cast<float2*>(
        part + ((size_t)(tok0 + r) * KSPLIT + ks) * 128 + 2 * lane) = v;
  }
}

// ---------------------------------------------------------------------------
// Epilogue (R0/R4/R7-proven): one wave per token. Sum KSPLIT partials,
// softplus-noise, top-2 (desc value, asc index), softmax over 2, scatter.
// ---------------------------------------------------------------------------
__global__ __launch_bounds__(256) void router_epilogue(
    const float* __restrict__ part,      // [NTOK][KSPLIT][128]
    const float* __restrict__ noise_eps, // [NTOK][EE]
    float* __restrict__ out)
{
  const int t    = blockIdx.x * 4 + (threadIdx.x >> 6);
  const int lane = threadIdx.x & 63;

  const float* p = part + (size_t)t * KSPLIT * 128;
  float g = 0.0f, nraw = 0.0f;
#pragma unroll
  for (int s = 0; s < KSPLIT; ++s) {
    g    += p[s * 128 + lane];
    nraw += p[s * 128 + EE + lane];
  }
  const float ep = noise_eps[(size_t)t * EE + lane];

  const float sp = fmaxf(nraw, 0.0f) + log1pf(expf(-fabsf(nraw)));
  const float z  = fmaf(sp, ep, g);

  float v1 = z; int i1 = lane;
#pragma unroll
  for (int off = 32; off >= 1; off >>= 1) {
    const float ov = __shfl_xor(v1, off, 64);
    const int   oi = __shfl_xor(i1, off, 64);
    if (ov > v1 || (ov == v1 && oi < i1)) { v1 = ov; i1 = oi; }
  }
  float v2 = (lane == i1) ? -INFINITY : z; int i2 = lane;
#pragma unroll
  for (int off = 32; off >= 1; off >>= 1) {
    const float ov = __shfl_xor(v2, off, 64);
    const int   oi = __shfl_xor(i2, off, 64);
    if (ov > v2 || (ov == v2 && oi < i2)) { v2 = ov; i2 = oi; }
  }

  const float e2 = expf(v2 - v1);
  const float denom = 1.0f + e2;
  const float p1 = 1.0f / denom;
  const float p2 = e2 / denom;

  out[PROB_OFF + (size_t)t * EE + lane] =
      (lane == i1) ? p1 : ((lane == i2) ? p2 : 0.0f);

  if (lane == 0) {
    out[IDX_OFF + t * 2 + 0] = (float)i1;
    out[IDX_OFF + t * 2 + 1] = (float)i2;
  }

  out[MASK_OFF + 0 * MASK_K_STRIDE + (size_t)t * EE + lane] = (lane == i1) ? 1.0f : 0.0f;
  out[MASK_OFF + 1 * MASK_K_STRIDE + (size_t)t * EE + lane] = (lane == i2) ? 1.0f : 0.0f;
}

// ---------------------------------------------------------------------------
extern "C" void kernel_launch(void* const* d_in, const int* in_sizes, int n_in,
                              void* d_out, int out_size, void* d_ws, size_t ws_size,
                              hipStream_t stream) {
  const float* x   = (const float*)d_in[0];
  const float* eps = (const float*)d_in[1];
  const float* wg  = (const float*)d_in[2];
  const float* wn  = (const float*)d_in[3];

  unsigned char* wsb = (unsigned char*)d_ws;            // 1 MB weight frags
  float* part = (float*)(wsb + (1 << 20));              // 16 MB partials

  prep_w<<<dim3(128), dim3(256), 0, stream>>>(wg, wn, wsb);
  router_gemm<<<dim3(NTOK / BM, KSPLIT), dim3(512), 0, stream>>>(x, wsb, part);
  router_epilogue<<<dim3(NTOK / 4), dim3(256), 0, stream>>>(part, eps,
                                                            (float*)d_out);
}

// Round 9
// 122.525 us; speedup vs baseline: 1.0489x; 1.0076x over previous
//
#include <hip/hip_runtime.h>
#include <math.h>

// Problem constants
#define DD     2048
#define EE     64
#define NTOK   8192
#define BM     64               // tokens per m-tile
#define KSPLIT 4                // K-split across blockIdx.y
#define KQ     512              // k per block
#define BK     32               // k per staged chunk
#define NCH    (KQ / BK)        // 16 chunks

// Output layout (all read back as float32 by harness)
#define PROB_OFF 0
#define IDX_OFF  524288
#define MASK_OFF 540672
#define MASK_K_STRIDE (NTOK * EE)

// LDS: 3-deep pipeline. xbuf[3] @ 0/8K/16K (8 KB), bbuf[3] @ 24K/40K/56K (16 KB)
#define XBUF_OFF(b) ((b) * 8192)
#define BBUF_OFF(b) (24576 + (b) * 16384)
#define LDS_BYTES   73728        // 72 KB -> 2 blocks/CU

typedef __bf16 bf16x8 __attribute__((ext_vector_type(8)));
typedef float  f32x16 __attribute__((ext_vector_type(16)));

__device__ __forceinline__ unsigned f2bf_rne(float f) {
  unsigned u = __float_as_uint(f);
  return (u + 0x7fffu + ((u >> 16) & 1u)) >> 16;   // low 16 bits = bf16
}
__device__ __forceinline__ float bf2f(unsigned h) {
  return __uint_as_float(h << 16);
}

// async 16B global->LDS DMA (no VGPR round-trip; tracked by vmcnt)
__device__ __forceinline__ void gl_lds16(const void* g, void* l) {
  __builtin_amdgcn_global_load_lds(
      (const __attribute__((address_space(1))) unsigned int*)g,
      (__attribute__((address_space(3))) unsigned int*)l,
      16, 0, 0);
}

// ---------------------------------------------------------------------------
// prep_w: weights -> MFMA-fragment-ready bf16 hi/lo in workspace (1 MB).
// Fragment bijection (validated end-to-end by R1-R8 passes):
//   slot (g, nt, mat, lane, i)  <->  B[k][c],  k = 16*g + 8*(lane>>5) + i,
//   c = 32*nt + (lane&31),  (c<64 -> gate, else noise).
// Byte addr = ((g*4 + nt)*2 + mat)*1024 + lane*16 + 2*i.
// ---------------------------------------------------------------------------
__global__ __launch_bounds__(256) void prep_w(
    const float* __restrict__ wg, const float* __restrict__ wn,
    unsigned char* __restrict__ wsb)
{
  const int t  = blockIdx.x * 256 + threadIdx.x;   // 0..32767
  const int l  = t & 63;
  const int nt = (t >> 6) & 3;
  const int g  = t >> 8;                           // 0..127 (16-k steps)
  const int colg = nt * 32 + (l & 31);             // 0..127
  const int kb   = g * 16 + 8 * (l >> 5);
  const float* wsrc = (colg < EE) ? (wg + colg) : (wn + (colg - EE));

  unsigned hv[8], lv[8];
#pragma unroll
  for (int i = 0; i < 8; ++i) {
    const float v = wsrc[(size_t)(kb + i) * EE];
    const unsigned h = f2bf_rne(v);
    hv[i] = h;
    lv[i] = f2bf_rne(v - bf2f(h));
  }
  uint4 hq, lq;
  hq.x = hv[0] | (hv[1] << 16); hq.y = hv[2] | (hv[3] << 16);
  hq.z = hv[4] | (hv[5] << 16); hq.w = hv[6] | (hv[7] << 16);
  lq.x = lv[0] | (lv[1] << 16); lq.y = lv[2] | (lv[3] << 16);
  lq.z = lv[4] | (lv[5] << 16); lq.w = lv[6] | (lv[7] << 16);

  const size_t base = ((size_t)(g * 4 + nt) * 2) * 1024 + (size_t)l * 16;
  *reinterpret_cast<uint4*>(wsb + base)        = hq;   // hi
  *reinterpret_cast<uint4*>(wsb + base + 1024) = lq;   // lo
}

union BF8 { bf16x8 v; ushort u[8]; };

__device__ __forceinline__ void cvt_hilo(const float4& a, const float4& b,
                                         bf16x8& hi, bf16x8& lo) {
  const float f[8] = {a.x, a.y, a.z, a.w, b.x, b.y, b.z, b.w};
  BF8 H, L;
#pragma unroll
  for (int i = 0; i < 8; ++i) {
    const unsigned u = __float_as_uint(f[i]);
    H.u[i] = (ushort)(u >> 16);                                 // exact prefix
    L.v[i] = (__bf16)(f[i] - __uint_as_float(u & 0xffff0000u)); // residual, RNE
  }
  hi = H.v; lo = L.v;
}

__device__ __forceinline__ bf16x8 bc(const uint4& q) {
  return __builtin_bit_cast(bf16x8, q);
}

// ---------------------------------------------------------------------------
// router_gemm v9: R8 geometry, counted-vmcnt pipeline (T3+T4). R6-R8 post-
// mortem: __syncthreads forces vmcnt(0) drain every chunk (m97 ceiling
// mechanism); time was invariant to bytes/occupancy because each of 16
// chunks serially pays a DMA round trip. Here: 3 LDS buffers, prologue
// stages chunks 0-2 (9 gl_lds/wave in flight), loop does
//   s_waitcnt vmcnt(6)  -> chunk c landed (oldest-first, m135), c+1/c+2
//   s_barrier           -> all waves' chunk-c DMA landed      stay in flight
//   compute c; lgkmcnt(0); s_barrier -> buffer free
//   stage c+3 into buf[c%3]
// vmcnt never drains to 0 in-loop (tail: 6/3/0). sched_barrier(0) pins
// phase order (m152). Staging/compute/tail bodies byte-identical to R8.
// ---------------------------------------------------------------------------
__global__ __launch_bounds__(512, 4) void router_gemm(
    const float* __restrict__ x,
    const unsigned char* __restrict__ wsb,
    float* __restrict__ part)          // [NTOK][KSPLIT][128]
{
  __shared__ unsigned char lds[LDS_BYTES];

  const int tid  = threadIdx.x;
  const int wid  = tid >> 6;           // 0..7
  const int lane = tid & 63;
  const int mh   = wid >> 2;           // m-sub (32 tokens)
  const int nt   = wid & 3;            // 32-col tile
  const int tok0 = blockIdx.x * BM;
  const int ks   = blockIdx.y;
  const int kbase = ks * KQ;

  // ---- staging roles (validated R8) ----
  const int xrow  = tid >> 3;
  const int xslot = tid & 7;
  const float* xsrc = x + (size_t)(tok0 + xrow) * DD + kbase
                        + ((xslot ^ (xrow & 7)) << 2);
  const unsigned char* bsrc = wsb + (size_t)(ks * (KQ / 16)) * 8192
                                  + (size_t)tid * 16;

  // ---- compute-role constants ----
  const int arow = lane & 31;
  const int atl  = lane >> 5;
  const int xswz = arow & 7;

  f32x16 acc = {0.f,0.f,0.f,0.f,0.f,0.f,0.f,0.f,
                0.f,0.f,0.f,0.f,0.f,0.f,0.f,0.f};

  // stage chunk cc into buffer b (3 gl_lds per thread = 3 vmcnt/wave)
  auto STAGE = [&](int cc, int b) {
    gl_lds16(xsrc + cc * BK, &lds[XBUF_OFF(b) + tid * 16]);
    const unsigned char* bs = bsrc + (size_t)cc * 16384;
    gl_lds16(bs,        &lds[BBUF_OFF(b) + tid * 16]);
    gl_lds16(bs + 8192, &lds[BBUF_OFF(b) + 8192 + tid * 16]);
  };

  // ---- prologue: fill the 3-deep pipeline (no drain) ----
  STAGE(0, 0);
  STAGE(1, 1);
  STAGE(2, 2);

#pragma unroll
  for (int c = 0; c < NCH; ++c) {
    // wait for chunk c only; keep later chunks' DMA in flight
    if (c <= NCH - 3)      asm volatile("s_waitcnt vmcnt(6)" ::: "memory");
    else if (c == NCH - 2) asm volatile("s_waitcnt vmcnt(3)" ::: "memory");
    else                   asm volatile("s_waitcnt vmcnt(0)" ::: "memory");
    __builtin_amdgcn_s_barrier();        // all waves' chunk-c data in LDS
    __builtin_amdgcn_sched_barrier(0);

    // ---- compute chunk c from buffer c%3 (LDS only) ----
    const unsigned char* xb = &lds[XBUF_OFF(c % 3)];
    const unsigned char* bb = &lds[BBUF_OFF(c % 3)];
#pragma unroll
    for (int s = 0; s < 2; ++s) {
      const int sl0 = (4 * s + 2 * atl) ^ xswz;
      const int sl1 = (4 * s + 2 * atl + 1) ^ xswz;
      const float4 xa = *reinterpret_cast<const float4*>(
          xb + (32 * mh + arow) * 128 + sl0 * 16);
      const float4 xv = *reinterpret_cast<const float4*>(
          xb + (32 * mh + arow) * 128 + sl1 * 16);
      const unsigned char* q = bb + s * 8192 + nt * 2048 + lane * 16;
      const uint4 bh = *reinterpret_cast<const uint4*>(q);
      const uint4 bl = *reinterpret_cast<const uint4*>(q + 1024);

      bf16x8 ahi, alo;
      cvt_hilo(xa, xv, ahi, alo);
      acc = __builtin_amdgcn_mfma_f32_32x32x16_bf16(ahi, bc(bh), acc, 0, 0, 0);
      acc = __builtin_amdgcn_mfma_f32_32x32x16_bf16(ahi, bc(bl), acc, 0, 0, 0);
      acc = __builtin_amdgcn_mfma_f32_32x32x16_bf16(alo, bc(bh), acc, 0, 0, 0);
    }

    asm volatile("s_waitcnt lgkmcnt(0)" ::: "memory");  // my reads consumed
    __builtin_amdgcn_s_barrier();        // all waves done reading buf[c%3]
    __builtin_amdgcn_sched_barrier(0);

    if (c + 3 < NCH) STAGE(c + 3, c % 3);   // overwrite freed buffer
  }

  // ---- tail: acc -> LDS [64][128] f32 (overlays buffers), coalesced store ----
  // C/D map (validated R1-R8): col = lane&31, row = (q&3)+8*(q>>2)+4*(lane>>5)
  float* Lp = reinterpret_cast<float*>(lds);
  const int ccol = nt * 32 + (lane & 31);
#pragma unroll
  for (int q = 0; q < 16; ++q) {
    const int r = 32 * mh + (q & 3) + 8 * (q >> 2) + 4 * atl;
    Lp[r * 128 + ccol] = acc[q];
  }
  __syncthreads();
#pragma unroll
  for (int rr = 0; rr < 8; ++rr) {
    const int r = 8 * wid + rr;
    const float2 v = *reinterpret_cast<const float2*>(&Lp[r * 128 + 2 * lane]);
    *reinterpret_cast<float2*>(
        part + ((size_t)(tok0 + r) * KSPLIT + ks) * 128 + 2 * lane) = v;
  }
}

// ---------------------------------------------------------------------------
// Epilogue (R0/R4/R8-proven): one wave per token. Sum KSPLIT partials,
// softplus-noise, top-2 (desc value, asc index), softmax over 2, scatter.
// ---------------------------------------------------------------------------
__global__ __launch_bounds__(256) void router_epilogue(
    const float* __restrict__ part,      // [NTOK][KSPLIT][128]
    const float* __restrict__ noise_eps, // [NTOK][EE]
    float* __restrict__ out)
{
  const int t    = blockIdx.x * 4 + (threadIdx.x >> 6);
  const int lane = threadIdx.x & 63;

  const float* p = part + (size_t)t * KSPLIT * 128;
  float g = 0.0f, nraw = 0.0f;
#pragma unroll
  for (int s = 0; s < KSPLIT; ++s) {
    g    += p[s * 128 + lane];
    nraw += p[s * 128 + EE + lane];
  }
  const float ep = noise_eps[(size_t)t * EE + lane];

  const float sp = fmaxf(nraw, 0.0f) + log1pf(expf(-fabsf(nraw)));
  const float z  = fmaf(sp, ep, g);

  float v1 = z; int i1 = lane;
#pragma unroll
  for (int off = 32; off >= 1; off >>= 1) {
    const float ov = __shfl_xor(v1, off, 64);
    const int   oi = __shfl_xor(i1, off, 64);
    if (ov > v1 || (ov == v1 && oi < i1)) { v1 = ov; i1 = oi; }
  }
  float v2 = (lane == i1) ? -INFINITY : z; int i2 = lane;
#pragma unroll
  for (int off = 32; off >= 1; off >>= 1) {
    const float ov = __shfl_xor(v2, off, 64);
    const int   oi = __shfl_xor(i2, off, 64);
    if (ov > v2 || (ov == v2 && oi < i2)) { v2 = ov; i2 = oi; }
  }

  const float e2 = expf(v2 - v1);
  const float denom = 1.0f + e2;
  const float p1 = 1.0f / denom;
  const float p2 = e2 / denom;

  out[PROB_OFF + (size_t)t * EE + lane] =
      (lane == i1) ? p1 : ((lane == i2) ? p2 : 0.0f);

  if (lane == 0) {
    out[IDX_OFF + t * 2 + 0] = (float)i1;
    out[IDX_OFF + t * 2 + 1] = (float)i2;
  }

  out[MASK_OFF + 0 * MASK_K_STRIDE + (size_t)t * EE + lane] = (lane == i1) ? 1.0f : 0.0f;
  out[MASK_OFF + 1 * MASK_K_STRIDE + (size_t)t * EE + lane] = (lane == i2) ? 1.0f : 0.0f;
}

// ---------------------------------------------------------------------------
extern "C" void kernel_launch(void* const* d_in, const int* in_sizes, int n_in,
                              void* d_out, int out_size, void* d_ws, size_t ws_size,
                              hipStream_t stream) {
  const float* x   = (const float*)d_in[0];
  const float* eps = (const float*)d_in[1];
  const float* wg  = (const float*)d_in[2];
  const float* wn  = (const float*)d_in[3];

  unsigned char* wsb = (unsigned char*)d_ws;            // 1 MB weight frags
  float* part = (float*)(wsb + (1 << 20));              // 16 MB partials

  prep_w<<<dim3(128), dim3(256), 0, stream>>>(wg, wn, wsb);
  router_gemm<<<dim3(NTOK / BM, KSPLIT), dim3(512), 0, stream>>>(x, wsb, part);
  router_epilogue<<<dim3(NTOK / 4), dim3(256), 0, stream>>>(part, eps,
                                                            (float*)d_out);
}